// Round 4
// baseline (554.147 us; speedup 1.0000x reference)
//
#include <hip/hip_runtime.h>

#define BB 32
#define LL 2048
#define DD 128
#define SCALE 0.08838834764831845f
#define DELTA 0.012f
#define CAPA 4096

typedef _Float16 half8 __attribute__((ext_vector_type(8)));
typedef float f4 __attribute__((ext_vector_type(4)));

struct __align__(32) RB { unsigned grow, i1, i2; float p1, p2; unsigned pad[3]; };

// Load one 16-key tile's B-fragment raw floats (8 x f4 per lane).
// Lane l covers K[key0 + (l&15)][kg*8 .. kg*8+7] for each 32-wide d-block.
#define LOADT(Rg, T) do {                                                   \
    const float* kp_ = kbat + ((size_t)(((T) << 4) + col)) * DD + (kg << 3);\
    Rg##0 = *(const f4*)(kp_);       Rg##1 = *(const f4*)(kp_ + 4);         \
    Rg##2 = *(const f4*)(kp_ + 32);  Rg##3 = *(const f4*)(kp_ + 36);        \
    Rg##4 = *(const f4*)(kp_ + 64);  Rg##5 = *(const f4*)(kp_ + 68);        \
    Rg##6 = *(const f4*)(kp_ + 96);  Rg##7 = *(const f4*)(kp_ + 100);       \
} while (0)

#define CVT8(h_, x_, y_) do {                                               \
    h_[0]=(_Float16)x_[0]; h_[1]=(_Float16)x_[1];                           \
    h_[2]=(_Float16)x_[2]; h_[3]=(_Float16)x_[3];                           \
    h_[4]=(_Float16)y_[0]; h_[5]=(_Float16)y_[1];                           \
    h_[6]=(_Float16)y_[2]; h_[7]=(_Float16)y_[3];                           \
} while (0)

// MFMA the tile, update top-3/sum state, and emit one interleaved zero-store.
#define STEP(Rg, T) do {                                                    \
    f4 acc = {0.f, 0.f, 0.f, 0.f};                                          \
    half8 hb;                                                               \
    CVT8(hb, Rg##0, Rg##1);                                                 \
    acc = __builtin_amdgcn_mfma_f32_16x16x32_f16(qa[0], hb, acc, 0, 0, 0);  \
    CVT8(hb, Rg##2, Rg##3);                                                 \
    acc = __builtin_amdgcn_mfma_f32_16x16x32_f16(qa[1], hb, acc, 0, 0, 0);  \
    CVT8(hb, Rg##4, Rg##5);                                                 \
    acc = __builtin_amdgcn_mfma_f32_16x16x32_f16(qa[2], hb, acc, 0, 0, 0);  \
    CVT8(hb, Rg##6, Rg##7);                                                 \
    acc = __builtin_amdgcn_mfma_f32_16x16x32_f16(qa[3], hb, acc, 0, 0, 0);  \
    const int key_ = ((T) << 4) + col;                                      \
    _Pragma("unroll")                                                       \
    for (int j = 0; j < 4; ++j) {                                           \
        float s = acc[j];                                                   \
        if (s > m3[j]) {                                                    \
            if (s > m1[j]) {                                                \
                m3[j]=m2[j]; m2[j]=m1[j]; i2[j]=i1[j];                      \
                sm[j] *= __expf(m1[j] - s);                                 \
                m1[j]=s; i1[j]=key_;                                        \
            } else if (s > m2[j]) {                                         \
                m3[j]=m2[j]; m2[j]=s; i2[j]=key_;                           \
            } else m3[j]=s;                                                 \
        }                                                                   \
        sm[j] += __expf(s - m1[j]);                                         \
    }                                                                       \
    { f4 z_ = {0.f,0.f,0.f,0.f};                                            \
      *(f4*)(zb + (((size_t)((T) >> 3)) << 11) +                            \
             ((((((T) & 7) << 6) + lane)) << 2)) = z_; }                    \
} while (0)

// ---------------- main kernel: barrier-free per-wave flash argmax ----------------
__global__ __launch_bounds__(256, 3)
void attn_main(const float* __restrict__ Q, const float* __restrict__ K,
               const float* __restrict__ V, float* __restrict__ out,
               unsigned* __restrict__ cntA, unsigned* __restrict__ cntB,
               uint2* __restrict__ listA, RB* __restrict__ listB, int capB)
{
    // bijective XCD-chunked swizzle: all 32 q-tiles of a batch on one XCD
    const int P    = blockIdx.x;
    const int slot = P >> 3;
    const int b    = (P & 7) + ((slot >> 5) << 3);   // 0..31
    const int q0   = (slot & 31) << 6;               // 0..2047 step 64
    const int tid  = threadIdx.x;
    const int wv   = tid >> 6;
    const int lane = tid & 63;
    const int col  = lane & 15;      // key-column within 16-wide tile
    const int kg   = lane >> 4;      // k-slice group (0..3)
    const int wq0  = q0 + (wv << 4); // this wave's 16 q-rows

    const float* kbat = K + (size_t)b * LL * DD;
    float* outA = out + (size_t)BB * LL * DD;
    float* zb   = outA + ((size_t)(b * LL + wq0)) * LL;  // wave's 16 attn rows

    // Q A-fragments (pre-scaled), lane holds Q[wq0+col][db*32 + kg*8 + j]
    half8 qa[4];
    {
        const float* qsrc = Q + ((size_t)b * LL + wq0 + col) * DD + (kg << 3);
#pragma unroll
        for (int db = 0; db < 4; ++db) {
            f4 x = *(const f4*)(qsrc + db * 32);
            f4 y = *(const f4*)(qsrc + db * 32 + 4);
            half8 h;
            h[0]=(_Float16)(x[0]*SCALE); h[1]=(_Float16)(x[1]*SCALE);
            h[2]=(_Float16)(x[2]*SCALE); h[3]=(_Float16)(x[3]*SCALE);
            h[4]=(_Float16)(y[0]*SCALE); h[5]=(_Float16)(y[1]*SCALE);
            h[6]=(_Float16)(y[2]*SCALE); h[7]=(_Float16)(y[3]*SCALE);
            qa[db] = h;
        }
    }

    float m1[4], m2[4], m3[4], sm[4];
    int   i1[4], i2[4];
#pragma unroll
    for (int j = 0; j < 4; ++j) { m1[j]=m2[j]=m3[j]=-1e30f; sm[j]=0.f; i1[j]=i2[j]=0; }

    // software-pipelined key loop: 128 tiles of 16 keys, prefetch 1 tile ahead
    f4 A0,A1,A2,A3,A4,A5,A6,A7;
    f4 B0,B1,B2,B3,B4,B5,B6,B7;
    LOADT(A, 0);
    for (int t = 0; t < 128; t += 2) {
        LOADT(B, t + 1);
        STEP(A, t);
        const int tn = (t + 2 < 128) ? (t + 2) : 127;   // harmless dup at tail
        LOADT(A, tn);
        STEP(B, t + 1);
    }

    // butterfly merge across the 16 column-lanes (all lanes converge)
#pragma unroll
    for (int off = 1; off < 16; off <<= 1) {
#pragma unroll
        for (int j = 0; j < 4; ++j) {
            float om1 = __shfl_xor(m1[j], off);
            float om2 = __shfl_xor(m2[j], off);
            float om3 = __shfl_xor(m3[j], off);
            float osm = __shfl_xor(sm[j], off);
            int   oi1 = __shfl_xor(i1[j], off);
            int   oi2 = __shfl_xor(i2[j], off);
            float Mn = fmaxf(m1[j], om1);
            sm[j] = sm[j]*__expf(m1[j]-Mn) + osm*__expf(om1-Mn);
            if (om1 > m1[j]) {
                float t2;  int ti;
                t2=m1[j]; m1[j]=om1; om1=t2;
                t2=m2[j]; m2[j]=om2; om2=t2;
                t2=m3[j]; m3[j]=om3; om3=t2;
                ti=i1[j]; i1[j]=oi1; oi1=ti;
                ti=i2[j]; i2[j]=oi2; oi2=ti;
            }
            if (om1 > m2[j]) { m3[j]=fmaxf(m2[j], om2); m2[j]=om1; i2[j]=oi1; }
            else             { m3[j]=fmaxf(m3[j], om1); }
        }
    }

    // drain this wave's zero-stores so the scatter below lands after them
    asm volatile("s_waitcnt vmcnt(0)" ::: "memory");

    if (col == 0) {
#pragma unroll
        for (int j = 0; j < 4; ++j) {
            const int r    = (kg << 2) + j;              // row within wave
            const int grow = b * LL + wq0 + r;
            float p1 = 1.f / sm[j];
            outA[(size_t)grow * LL + i1[j]] = p1;
            float g13 = m1[j] - m3[j];
            float g12 = m1[j] - m2[j];
            if (g13 <= DELTA) {
                unsigned slotA = atomicAdd(cntA, 1u);
                if (slotA < CAPA) listA[slotA] = make_uint2((unsigned)grow, (unsigned)i1[j]);
            } else if (g12 <= DELTA) {
                unsigned slotB = atomicAdd(cntB, 1u);
                if (slotB < (unsigned)capB) {
                    RB rb; rb.grow=(unsigned)grow; rb.i1=(unsigned)i1[j]; rb.i2=(unsigned)i2[j];
                    rb.p1=p1; rb.p2=__expf(m2[j]-m1[j])*p1;
                    rb.pad[0]=rb.pad[1]=rb.pad[2]=0;
                    listB[slotB] = rb;
                }
            }
        }
    }

    // output rows: each 16-lane group writes its 4 rows (all lanes hold merged state)
#pragma unroll
    for (int j = 0; j < 4; ++j) {
        const int r    = (kg << 2) + j;
        const int grow = b * LL + wq0 + r;
        float p1 = 1.f / sm[j];
        const float* vs = V + ((size_t)(b * LL + i1[j])) * DD + (col << 3);
        float* dst = out + (size_t)grow * DD + (col << 3);
        f4 v0 = *(const f4*)(vs);
        f4 v1 = *(const f4*)(vs + 4);
        *(f4*)(dst)     = v0 * p1;
        *(f4*)(dst + 4) = v1 * p1;
    }
}

// ---------------- fix-up B: two-candidate fp64 compare ----------------
__global__ __launch_bounds__(64)
void fix_pair(const float* __restrict__ Q, const float* __restrict__ K,
              const float* __restrict__ V, float* __restrict__ out,
              const unsigned* __restrict__ cntB, const RB* __restrict__ listB, int capB)
{
    int n = (int)min(*cntB, (unsigned)capB);
    float* outA = out + (size_t)BB * LL * DD;
    int lane = threadIdx.x;
    for (int e = blockIdx.x; e < n; e += gridDim.x) {
        RB r = listB[e];
        int b = (int)(r.grow >> 11);
        const float* q  = Q + (size_t)r.grow * DD;
        const float* k1 = K + ((size_t)(b << 11) + r.i1) * DD;
        const float* k2 = K + ((size_t)(b << 11) + r.i2) * DD;
        double a1 = 0.0, a2 = 0.0;
        for (int d = lane; d < DD; d += 64) {
            double qd = (double)q[d];
            a1 += qd * (double)k1[d];
            a2 += qd * (double)k2[d];
        }
#pragma unroll
        for (int off = 32; off > 0; off >>= 1) {
            a1 += __shfl_down(a1, off);
            a2 += __shfl_down(a2, off);
        }
        int sel = (a2 > a1) ? 1 : 0;
        sel = __shfl(sel, 0);
        if (sel) {
            if (lane == 0) {
                outA[(size_t)r.grow * LL + r.i1] = 0.f;
                outA[(size_t)r.grow * LL + r.i2] = r.p2;
            }
            const float* vs = V + ((size_t)(b << 11) + r.i2) * DD;
            float* dst = out + (size_t)r.grow * DD;
            for (int d = lane; d < DD; d += 64) dst[d] = r.p2 * vs[d];
        }
    }
}

// ---------------- fix-up A: full fp64 row rescan ----------------
__global__ __launch_bounds__(256)
void fix_full(const float* __restrict__ Q, const float* __restrict__ K,
              const float* __restrict__ V, float* __restrict__ out,
              const unsigned* __restrict__ cntA, const uint2* __restrict__ listA)
{
    __shared__ float  qsh[DD];
    __shared__ double rbuf[256];
    __shared__ int    ibuf[256];
    int n = (int)min(*cntA, (unsigned)CAPA);
    float* outA = out + (size_t)BB * LL * DD;
    int tid = threadIdx.x;
    for (int e = blockIdx.x; e < n; e += gridDim.x) {
        uint2 en = listA[e];
        int grow = (int)en.x, iold = (int)en.y;
        int b = grow >> 11;
        __syncthreads();
        if (tid < DD) qsh[tid] = Q[(size_t)grow * DD + tid];
        __syncthreads();
        double ls[8];
        double best = -1e300; int bidx = 0;
#pragma unroll
        for (int kk = 0; kk < 8; ++kk) {
            int key = (kk << 8) + tid;
            const float* kr = K + ((size_t)(b << 11) + key) * DD;
            double acc = 0.0;
            for (int d = 0; d < DD; ++d) acc += (double)qsh[d] * (double)kr[d];
            acc *= (double)SCALE;
            ls[kk] = acc;
            if (acc > best) { best = acc; bidx = key; }
        }
        rbuf[tid] = best; ibuf[tid] = bidx;
        __syncthreads();
        for (int s2 = 128; s2 > 0; s2 >>= 1) {
            if (tid < s2 && rbuf[tid + s2] > rbuf[tid]) { rbuf[tid]=rbuf[tid+s2]; ibuf[tid]=ibuf[tid+s2]; }
            __syncthreads();
        }
        double gbest = rbuf[0]; int gidx = ibuf[0];
        __syncthreads();
        double lsum = 0.0;
#pragma unroll
        for (int kk = 0; kk < 8; ++kk) lsum += exp(ls[kk] - gbest);
        rbuf[tid] = lsum;
        __syncthreads();
        for (int s2 = 128; s2 > 0; s2 >>= 1) {
            if (tid < s2) rbuf[tid] += rbuf[tid + s2];
            __syncthreads();
        }
        float p = (float)(1.0 / rbuf[0]);
        if (tid == 0) {
            outA[(size_t)grow * LL + iold] = 0.f;
            outA[(size_t)grow * LL + gidx] = p;
        }
        if (tid < DD) out[(size_t)grow * DD + tid] = p * V[((size_t)(b << 11) + gidx) * DD + tid];
        __syncthreads();
    }
}

extern "C" void kernel_launch(void* const* d_in, const int* in_sizes, int n_in,
                              void* d_out, int out_size, void* d_ws, size_t ws_size,
                              hipStream_t stream)
{
    const float* Q = (const float*)d_in[0];
    const float* K = (const float*)d_in[1];
    const float* V = (const float*)d_in[2];
    float* out = (float*)d_out;

    unsigned* cntA = (unsigned*)d_ws;
    unsigned* cntB = cntA + 1;
    uint2* listA = (uint2*)((char*)d_ws + 64);
    size_t offB = 64 + (size_t)CAPA * 8;          // 32832, 32B-aligned
    RB* listB = (RB*)((char*)d_ws + offB);
    int capB = 0;
    if (ws_size > offB + 32) capB = (int)((ws_size - offB) / 32);
    if (capB > 65536) capB = 65536;

    hipMemsetAsync(d_ws, 0, 8, stream);           // zero both counters (deterministic)
    hipLaunchKernelGGL(attn_main, dim3(BB * (LL / 64)), dim3(256), 0, stream,
                       Q, K, V, out, cntA, cntB, listA, listB, capB);
    hipLaunchKernelGGL(fix_full, dim3(256), dim3(256), 0, stream, Q, K, V, out, cntA, listA);
    hipLaunchKernelGGL(fix_pair, dim3(2048), dim3(64), 0, stream, Q, K, V, out, cntB, listB, capB);
}